// Round 20
// baseline (1677.563 us; speedup 1.0000x reference)
//
#include <hip/hip_runtime.h>

typedef unsigned short u16;
typedef __attribute__((ext_vector_type(8))) short bf16x8;
typedef __attribute__((ext_vector_type(4))) float f32x4;

#define TOK  8192
#define HD   2048
#define FFD  8192
#define NEXP 4
#define CAPE 4352   // per-expert padded row capacity = 17*256

__device__ __forceinline__ u16 f2bf(float f){
  unsigned u = __float_as_uint(f);
  u += 0x7fffu + ((u >> 16) & 1u);
  return (u16)(u >> 16);
}

__device__ __forceinline__ float gelu_tanh(float x){
  float u = 0.7978845608028654f * (x + 0.044715f * x * x * x);
  return 0.5f * x * (1.0f + tanhf(u));
}

__device__ __forceinline__ void gload_lds16(const void* g, void* l){
  __builtin_amdgcn_global_load_lds((const __attribute__((address_space(1))) void*)g,
                                   (__attribute__((address_space(3))) void*)l, 16, 0, 0);
}

__device__ __forceinline__ f32x4 mfma_bf16(bf16x8 a, bf16x8 b, f32x4 c){
  asm("v_mfma_f32_16x16x32_bf16 %0, %1, %2, %0" : "+v"(c) : "v"(a), "v"(b));
  return c;
}

// ---------------- conversions ----------------
__global__ __launch_bounds__(256) void cvt_to_bf16(const float* __restrict__ in,
                                                   u16* __restrict__ out, int n4){
  int i = blockIdx.x * 256 + threadIdx.x;
  if (i >= n4) return;
  float4 v = ((const float4*)in)[i];
  ushort4 o;
  o.x = f2bf(v.x); o.y = f2bf(v.y); o.z = f2bf(v.z); o.w = f2bf(v.w);
  ((ushort4*)out)[i] = o;
}

// in [R][C] f32 -> out [C][R] bf16, per blockIdx.z slab.
__global__ __launch_bounds__(256) void transpose_cvt(const float* __restrict__ in,
                                                     u16* __restrict__ out, int R, int C){
  __shared__ u16 t[64][138];
  in  += (size_t)blockIdx.z * R * C;
  out += (size_t)blockIdx.z * R * C;
  const int tx = threadIdx.x & 63;
  const int w  = threadIdx.x >> 6;
  const size_t r0 = (size_t)blockIdx.y * 128;
  const size_t c0 = (size_t)blockIdx.x * 64;
  #pragma unroll
  for (int i = 0; i < 32; i++){
    const int r = w * 32 + i;
    t[tx][r] = f2bf(in[(r0 + r) * C + c0 + tx]);
  }
  __syncthreads();
  #pragma unroll
  for (int j = 0; j < 16; j++){
    const int c = j * 4 + w;
    ushort2 o;
    o.x = t[c][2 * tx];
    o.y = t[c][2 * tx + 1];
    *(ushort2*)(out + (c0 + c) * (size_t)R + r0 + 2 * tx) = o;
  }
}

// ---------------- router ----------------
__global__ __launch_bounds__(256) void router_kernel(
    const float* __restrict__ X, const float* __restrict__ wg, const float* __restrict__ bg,
    float* __restrict__ probs, int* __restrict__ topi, float* __restrict__ gatew){
  int t = blockIdx.x;
  const float* x = X + (size_t)t * HD;
  float a0 = 0.f, a1 = 0.f, a2 = 0.f, a3 = 0.f;
  for (int h = threadIdx.x; h < HD; h += 256){
    float xv = x[h];
    float4 w = ((const float4*)wg)[h];
    a0 += xv * w.x; a1 += xv * w.y; a2 += xv * w.z; a3 += xv * w.w;
  }
  __shared__ float red[4][256];
  red[0][threadIdx.x] = a0; red[1][threadIdx.x] = a1;
  red[2][threadIdx.x] = a2; red[3][threadIdx.x] = a3;
  __syncthreads();
  for (int s = 128; s > 0; s >>= 1){
    if (threadIdx.x < (unsigned)s){
      #pragma unroll
      for (int e = 0; e < 4; e++) red[e][threadIdx.x] += red[e][threadIdx.x + s];
    }
    __syncthreads();
  }
  if (threadIdx.x == 0){
    float l[4], p[4];
    #pragma unroll
    for (int e = 0; e < 4; e++) l[e] = red[e][0] + bg[e];
    float mx = fmaxf(fmaxf(l[0], l[1]), fmaxf(l[2], l[3]));
    float s = 0.f;
    #pragma unroll
    for (int e = 0; e < 4; e++){ p[e] = expf(l[e] - mx); s += p[e]; }
    #pragma unroll
    for (int e = 0; e < 4; e++){ p[e] /= s; probs[t * 4 + e] = p[e]; }
    int e0 = 0;
    for (int e = 1; e < 4; e++) if (p[e] > p[e0]) e0 = e;
    int e1 = -1;
    for (int e = 0; e < 4; e++){ if (e == e0) continue; if (e1 < 0 || p[e] > p[e1]) e1 = e; }
    float g = p[e0] + p[e1];
    topi[t * 2] = e0; topi[t * 2 + 1] = e1;
    #pragma unroll
    for (int e = 0; e < 4; e++)
      gatew[(size_t)e * TOK + t] = (e == e0) ? p[e0] / g : (e == e1) ? p[e1] / g : 0.f;
  }
}

// ---------------- sorted token lists (deterministic ballot compaction) ----------------
__global__ __launch_bounds__(256) void compact_stage(const int* __restrict__ topi,
                                                     int* __restrict__ stage,   // [4][32][256]
                                                     int* __restrict__ cnum){   // [4][32]
  const int c = blockIdx.x, tid = threadIdx.x;
  const int t = c * 256 + tid;
  const int lane = tid & 63, w = tid >> 6;
  const int e0 = topi[t * 2], e1 = topi[t * 2 + 1];
  __shared__ int wcnt[4][4], woff[4][4];
  int pos[4]; bool sel[4];
  #pragma unroll
  for (int e = 0; e < 4; e++){
    sel[e] = (e0 == e) || (e1 == e);
    unsigned long long m = __ballot(sel[e]);
    pos[e] = __popcll(m & ((1ull << lane) - 1ull));
    if (lane == 0) wcnt[e][w] = __popcll(m);
  }
  __syncthreads();
  if (tid < 4){
    int s = 0;
    #pragma unroll
    for (int ww = 0; ww < 4; ww++){ woff[tid][ww] = s; s += wcnt[tid][ww]; }
    cnum[tid * 32 + c] = s;
  }
  __syncthreads();
  #pragma unroll
  for (int e = 0; e < 4; e++)
    if (sel[e]) stage[(e * 32 + c) * 256 + woff[e][w] + pos[e]] = t;
}

__global__ __launch_bounds__(64) void scan_chunks(const int* __restrict__ cnum,
                                                  int* __restrict__ coff,   // [4][32]
                                                  int* __restrict__ cnt){   // [4]
  if (threadIdx.x < 4){
    int e = threadIdx.x, s = 0;
    for (int c = 0; c < 32; c++){ coff[e * 32 + c] = s; s += cnum[e * 32 + c]; }
    cnt[e] = s;
  }
}

__global__ __launch_bounds__(256) void compact_write(const int* __restrict__ stage,
                                                     const int* __restrict__ cnum,
                                                     const int* __restrict__ coff,
                                                     int* __restrict__ lists){
  const int c = blockIdx.x, tid = threadIdx.x;
  #pragma unroll
  for (int e = 0; e < 4; e++){
    const int n = cnum[e * 32 + c];
    if (tid < n)
      lists[e * TOK + coff[e * 32 + c] + tid] = stage[(e * 32 + c) * 256 + tid];
  }
}

// ---------------- aux loss ----------------
__global__ __launch_bounds__(256) void aux_kernel(const float* __restrict__ probs,
                                                  const int* __restrict__ topi,
                                                  float* __restrict__ out_aux){
  __shared__ float sp[4][256];
  __shared__ float sc[4][256];
  float p[4] = {0,0,0,0}, c[4] = {0,0,0,0};
  for (int t = threadIdx.x; t < TOK; t += 256){
    #pragma unroll
    for (int e = 0; e < 4; e++) p[e] += probs[t * 4 + e];
    c[topi[t * 2]]     += 1.f;
    c[topi[t * 2 + 1]] += 1.f;
  }
  #pragma unroll
  for (int e = 0; e < 4; e++){ sp[e][threadIdx.x] = p[e]; sc[e][threadIdx.x] = c[e]; }
  __syncthreads();
  for (int s = 128; s > 0; s >>= 1){
    if (threadIdx.x < (unsigned)s){
      #pragma unroll
      for (int e = 0; e < 4; e++){
        sp[e][threadIdx.x] += sp[e][threadIdx.x + s];
        sc[e][threadIdx.x] += sc[e][threadIdx.x + s];
      }
    }
    __syncthreads();
  }
  if (threadIdx.x == 0){
    float aux = 0.f;
    #pragma unroll
    for (int e = 0; e < 4; e++)
      aux += (sc[e][0] / (float)(TOK * 2)) * (sp[e][0] / (float)TOK);
    *out_aux = 4.f * aux;
  }
}

// =====================================================================
// Unified m97-style MoE GEMM — exact R16 kernel (best measured: 1587).
// 128x128 tile, BK=64, 256 thr (4 waves 2x2), single-buffered 32 KB
// (5 blk/CU), chunked XCD map, swizzled stage+read (0 conflicts).
// R19->R20: host groups experts 2-at-a-time (z=2) with gemm1(g)->gemm2(g)
// interleave so the concurrent working set fits the 256 MB L3
// (R15/R16 counters: FETCH 2.17 GB vs ~400 MB unique = L3 thrash).
// EPI 0: Hb non-temporal stores. EPI 1: atomicAdd (deterministic —
// exactly 2 commutative f32 addends per element on a zeroed base).
// =====================================================================
template<int EPI, int N, int K, int ATOMIC>
__global__ __launch_bounds__(256) void gemm_97(
    const u16* __restrict__ A, const u16* __restrict__ BT,
    const int* __restrict__ lists, const int* __restrict__ cnt,
    const float* __restrict__ bias,
    u16* __restrict__ Hout,
    const float* __restrict__ gate, float* __restrict__ Cout)
{
  __shared__ __align__(16) u16 As[128 * 64];
  __shared__ __align__(16) u16 Bs[128 * 64];
  const int e = blockIdx.z;
  const int Mv = cnt[e];
  const int* rowidx = lists + (size_t)e * TOK;
  BT   += (size_t)e * N * K;
  bias += (size_t)e * N;
  if (EPI == 0) Hout += (size_t)e * CAPE * FFD;
  else        { A    += (size_t)e * CAPE * FFD; gate += (size_t)e * TOK; }

  const int gx = gridDim.x, gy = gridDim.y;
  const int orig = blockIdx.x + gx * blockIdx.y;
  const int xcd = orig & 7, rank = orig >> 3;          // gx*gy % 8 == 0
  const int bxl = rank / gy, by = rank % gy;
  const int bx = xcd * (gx >> 3) + bxl;                // chunked (R16)
  const int browg = by * 128;
  if (browg >= Mv) return;
  const size_t bcol = (size_t)bx * 128;

  const int tid = threadIdx.x, lane = tid & 63, w = tid >> 6;
  const int wr = w >> 1, wc = w & 1;
  const int l8 = lane >> 3;
  const int csw  = ((lane & 7) ^ l8) * 8;
  const int sw   = (lane & 7) * 8;
  const int h8   = ((lane >> 4) & 3) * 8;
  const int colk0 = h8 ^ sw, colk1 = (32 + h8) ^ sw;
  const int r16 = lane & 15;

  const u16* bsrc[4]; int bch[4];
  #pragma unroll
  for (int j = 0; j < 4; j++){
    int rb = j * 32 + w * 8;
    bch[j] = rb * 128;
    bsrc[j] = BT + (bcol + rb + l8) * (size_t)K + csw;
  }
  const u16* asrc[4]; int ach[4];
  #pragma unroll
  for (int q = 0; q < 4; q++){
    int rb = wr * 64 + q * 16 + wc * 8;
    ach[q] = rb * 128;
    int rl = browg + rb + l8;
    int ar;
    if (EPI == 0){
      if (rl > Mv - 1) rl = Mv - 1;
      ar = rowidx[rl];
    } else {
      ar = rl;
    }
    asrc[q] = A + (size_t)ar * K + csw;
  }

  f32x4 acc[4][4];
  #pragma unroll
  for (int m = 0; m < 4; m++)
    #pragma unroll
    for (int n = 0; n < 4; n++) acc[m][n] = (f32x4){0.f, 0.f, 0.f, 0.f};
  bf16x8 bC[8];

  const int NT = K / 64;
  for (int t = 0; t < NT; ++t){
    const size_t ko = (size_t)t * 64;
    __syncthreads();
    #pragma unroll
    for (int j = 0; j < 4; j++) gload_lds16(bsrc[j] + ko, (char*)Bs + bch[j]);
    #pragma unroll
    for (int q = 0; q < 4; q++) gload_lds16(asrc[q] + ko, (char*)As + ach[q]);
    __syncthreads();

    #pragma unroll
    for (int nf = 0; nf < 4; nf++){
      const u16* bp = Bs + (wc * 64 + nf * 16 + r16) * 64;
      bC[nf * 2]     = *(const bf16x8*)(bp + colk0);
      bC[nf * 2 + 1] = *(const bf16x8*)(bp + colk1);
    }
    #pragma unroll
    for (int m = 0; m < 4; m++){
      const u16* ap = As + (wr * 64 + m * 16 + r16) * 64;
      bf16x8 a0 = *(const bf16x8*)(ap + colk0);
      bf16x8 a1 = *(const bf16x8*)(ap + colk1);
      #pragma unroll
      for (int nf = 0; nf < 4; nf++){
        acc[m][nf] = mfma_bf16(a0, bC[nf * 2],     acc[m][nf]);
        acc[m][nf] = mfma_bf16(a1, bC[nf * 2 + 1], acc[m][nf]);
      }
    }
  }

  // epilogue
  const int cl = r16, rg = (lane >> 4) * 4;
  const size_t c0 = bcol + wc * 64;
  float bv[4];
  #pragma unroll
  for (int nf = 0; nf < 4; nf++) bv[nf] = bias[c0 + nf * 16 + cl];
  #pragma unroll
  for (int mf = 0; mf < 4; mf++){
    const int rbase = browg + wr * 64 + mf * 16 + rg;
    if (EPI == 0){
      #pragma unroll
      for (int nf = 0; nf < 4; nf++){
        const size_t col = c0 + nf * 16 + cl;
        #pragma unroll
        for (int j = 0; j < 4; j++){
          u16 hv = f2bf(gelu_tanh(acc[mf][nf][j] + bv[nf]));
          __builtin_nontemporal_store(hv, &Hout[(size_t)(rbase + j) * N + col]);
        }
      }
    } else {
      int   tok[4]; float gv[4];
      #pragma unroll
      for (int j = 0; j < 4; j++){
        const bool ok = (rbase + j) < Mv;
        tok[j] = ok ? rowidx[rbase + j] : -1;
        gv[j]  = ok ? gate[tok[j]] : 0.f;
      }
      #pragma unroll
      for (int nf = 0; nf < 4; nf++){
        const size_t col = c0 + nf * 16 + cl;
        #pragma unroll
        for (int j = 0; j < 4; j++){
          if (tok[j] >= 0){
            const size_t idx = (size_t)tok[j] * N + col;
            float y = gv[j] * (acc[mf][nf][j] + bv[nf]);
            if (ATOMIC) atomicAdd(Cout + idx, y);
            else        Cout[idx] += y;
          }
        }
      }
    }
  }
}

// ---------------- host ----------------
extern "C" void kernel_launch(void* const* d_in, const int* in_sizes, int n_in,
                              void* d_out, int out_size, void* d_ws, size_t ws_size,
                              hipStream_t stream){
  (void)in_sizes; (void)n_in;
  const float* X  = (const float*)d_in[0];
  const float* wg = (const float*)d_in[1];
  const float* bg = (const float*)d_in[2];
  const float* w1 = (const float*)d_in[3];
  const float* b1 = (const float*)d_in[4];
  const float* w2 = (const float*)d_in[5];
  const float* b2 = (const float*)d_in[6];
  float* out = (float*)d_out;

  char* ws = (char*)d_ws;
  size_t off = 0;
  auto alloc = [&](size_t b) -> char* {
    char* p = ws + off;
    off = (off + b + 255) & ~(size_t)255;
    return p;
  };
  u16*   Xb    = (u16*)  alloc((size_t)TOK * HD * 2);
  float* probs = (float*)alloc((size_t)TOK * 4 * 4);
  int*   topi  = (int*)  alloc((size_t)TOK * 2 * 4);
  float* gatew = (float*)alloc((size_t)NEXP * TOK * 4);
  int*   cnt   = (int*)  alloc((size_t)NEXP * 4);
  int*   lists = (int*)  alloc((size_t)NEXP * TOK * 4);
  int*   stage = (int*)  alloc((size_t)NEXP * 32 * 256 * 4);
  int*   cnum  = (int*)  alloc((size_t)NEXP * 32 * 4);
  int*   coff  = (int*)  alloc((size_t)NEXP * 32 * 4);
  const size_t common = off;

  const size_t w1t_all = (size_t)NEXP * FFD * HD * 2;
  const size_t w2t_all = (size_t)NEXP * HD * FFD * 2;
  const size_t hb_all  = (size_t)NEXP * CAPE * FFD * 2;
  const bool merged = ws_size >= common + w1t_all + w2t_all + hb_all + 1024;

  hipMemsetAsync(out, 0, (size_t)TOK * HD * sizeof(float), stream);

  cvt_to_bf16<<<(TOK * HD / 4 + 255) / 256, 256, 0, stream>>>(X, Xb, TOK * HD / 4);
  router_kernel<<<TOK, 256, 0, stream>>>(X, wg, bg, probs, topi, gatew);
  compact_stage<<<32, 256, 0, stream>>>(topi, stage, cnum);
  scan_chunks<<<1, 64, 0, stream>>>(cnum, coff, cnt);
  compact_write<<<32, 256, 0, stream>>>(stage, cnum, coff, lists);
  aux_kernel<<<1, 256, 0, stream>>>(probs, topi, out + (out_size - 1));

  if (merged){
    u16* W1T = (u16*)alloc(w1t_all);
    u16* W2T = (u16*)alloc(w2t_all);
    u16* Hb  = (u16*)alloc(hb_all);
    transpose_cvt<<<dim3(FFD / 64, HD / 128, NEXP), 256, 0, stream>>>(w1, W1T, HD, FFD);
    transpose_cvt<<<dim3(HD / 64, FFD / 128, NEXP), 256, 0, stream>>>(w2, W2T, FFD, HD);
    // 2-expert groups, gemm1(g) -> gemm2(g): working set per dispatch <= L3
    for (int g = 0; g < 2; ++g){
      const int e0 = 2 * g;
      gemm_97<0, FFD, HD, 0><<<dim3(FFD / 128, CAPE / 128, 2), 256, 0, stream>>>(
          Xb, W1T + (size_t)e0 * FFD * HD,
          lists + (size_t)e0 * TOK, cnt + e0, b1 + (size_t)e0 * FFD,
          Hb + (size_t)e0 * CAPE * FFD, nullptr, nullptr);
      gemm_97<1, HD, FFD, 1><<<dim3(HD / 128, CAPE / 128, 2), 256, 0, stream>>>(
          Hb + (size_t)e0 * CAPE * FFD, W2T + (size_t)e0 * HD * FFD,
          lists + (size_t)e0 * TOK, cnt + e0, b2 + (size_t)e0 * HD,
          nullptr, gatew + (size_t)e0 * TOK, out);
    }
  } else {
    u16* W1T = (u16*)alloc((size_t)FFD * HD * 2);
    u16* W2T = (u16*)alloc((size_t)HD * FFD * 2);
    u16* Hb  = (u16*)alloc((size_t)CAPE * FFD * 2);
    for (int e = 0; e < NEXP; ++e){
      transpose_cvt<<<dim3(FFD / 64, HD / 128, 1), 256, 0, stream>>>(
          w1 + (size_t)e * HD * FFD, W1T, HD, FFD);
      transpose_cvt<<<dim3(HD / 64, FFD / 128, 1), 256, 0, stream>>>(
          w2 + (size_t)e * FFD * HD, W2T, FFD, HD);
      gemm_97<0, FFD, HD, 0><<<dim3(FFD / 128, CAPE / 128, 1), 256, 0, stream>>>(
          Xb, W1T, lists + e * TOK, cnt + e, b1 + (size_t)e * FFD,
          Hb, nullptr, nullptr);
      gemm_97<1, HD, FFD, 0><<<dim3(HD / 128, CAPE / 128, 1), 256, 0, stream>>>(
          Hb, W2T, lists + e * TOK, cnt + e, b2 + (size_t)e * HD,
          nullptr, gatew + (size_t)e * TOK, out);
    }
  }
}

// Round 21
// 1575.397 us; speedup vs baseline: 1.0649x; 1.0649x over previous
//
#include <hip/hip_runtime.h>

typedef unsigned short u16;
typedef __attribute__((ext_vector_type(8))) short bf16x8;
typedef __attribute__((ext_vector_type(4))) float f32x4;

#define TOK  8192
#define HD   2048
#define FFD  8192
#define NEXP 4
#define CAPE 4352   // per-expert padded row capacity = 17*256

__device__ __forceinline__ u16 f2bf(float f){
  unsigned u = __float_as_uint(f);
  u += 0x7fffu + ((u >> 16) & 1u);
  return (u16)(u >> 16);
}

__device__ __forceinline__ float gelu_tanh(float x){
  float u = 0.7978845608028654f * (x + 0.044715f * x * x * x);
  return 0.5f * x * (1.0f + tanhf(u));
}

__device__ __forceinline__ void gload_lds16(const void* g, void* l){
  __builtin_amdgcn_global_load_lds((const __attribute__((address_space(1))) void*)g,
                                   (__attribute__((address_space(3))) void*)l, 16, 0, 0);
}

__device__ __forceinline__ f32x4 mfma_bf16(bf16x8 a, bf16x8 b, f32x4 c){
  asm("v_mfma_f32_16x16x32_bf16 %0, %1, %2, %0" : "+v"(c) : "v"(a), "v"(b));
  return c;
}

// in [R][C] f32 -> out [C][R] bf16, per blockIdx.z slab.
__global__ __launch_bounds__(256) void transpose_cvt(const float* __restrict__ in,
                                                     u16* __restrict__ out, int R, int C){
  __shared__ u16 t[64][138];
  in  += (size_t)blockIdx.z * R * C;
  out += (size_t)blockIdx.z * R * C;
  const int tx = threadIdx.x & 63;
  const int w  = threadIdx.x >> 6;
  const size_t r0 = (size_t)blockIdx.y * 128;
  const size_t c0 = (size_t)blockIdx.x * 64;
  #pragma unroll
  for (int i = 0; i < 32; i++){
    const int r = w * 32 + i;
    t[tx][r] = f2bf(in[(r0 + r) * C + c0 + tx]);
  }
  __syncthreads();
  #pragma unroll
  for (int j = 0; j < 16; j++){
    const int c = j * 4 + w;
    ushort2 o;
    o.x = t[c][2 * tx];
    o.y = t[c][2 * tx + 1];
    *(ushort2*)(out + (c0 + c) * (size_t)R + r0 + 2 * tx) = o;
  }
}

// ---------------- router (fused X->bf16 conversion: R21) ----------------
__global__ __launch_bounds__(256) void router_kernel(
    const float* __restrict__ X, const float* __restrict__ wg, const float* __restrict__ bg,
    float* __restrict__ probs, int* __restrict__ topi, float* __restrict__ gatew,
    u16* __restrict__ Xb){
  int t = blockIdx.x;
  const float4* x4  = (const float4*)(X + (size_t)t * HD);
  ushort4*      xb4 = (ushort4*)(Xb + (size_t)t * HD);
  const float4* wg4 = (const float4*)wg;               // wg[h][0..3]
  float a0 = 0.f, a1 = 0.f, a2 = 0.f, a3 = 0.f;
  #pragma unroll
  for (int it = 0; it < HD / 4 / 256; ++it){
    const int h4 = it * 256 + threadIdx.x;
    float4 xv = x4[h4];
    ushort4 o;
    o.x = f2bf(xv.x); o.y = f2bf(xv.y); o.z = f2bf(xv.z); o.w = f2bf(xv.w);
    xb4[h4] = o;
    float xe[4] = {xv.x, xv.y, xv.z, xv.w};
    #pragma unroll
    for (int j = 0; j < 4; j++){
      float4 w = wg4[h4 * 4 + j];
      a0 += xe[j] * w.x; a1 += xe[j] * w.y; a2 += xe[j] * w.z; a3 += xe[j] * w.w;
    }
  }
  __shared__ float red[4][256];
  red[0][threadIdx.x] = a0; red[1][threadIdx.x] = a1;
  red[2][threadIdx.x] = a2; red[3][threadIdx.x] = a3;
  __syncthreads();
  for (int s = 128; s > 0; s >>= 1){
    if (threadIdx.x < (unsigned)s){
      #pragma unroll
      for (int e = 0; e < 4; e++) red[e][threadIdx.x] += red[e][threadIdx.x + s];
    }
    __syncthreads();
  }
  if (threadIdx.x == 0){
    float l[4], p[4];
    #pragma unroll
    for (int e = 0; e < 4; e++) l[e] = red[e][0] + bg[e];
    float mx = fmaxf(fmaxf(l[0], l[1]), fmaxf(l[2], l[3]));
    float s = 0.f;
    #pragma unroll
    for (int e = 0; e < 4; e++){ p[e] = expf(l[e] - mx); s += p[e]; }
    #pragma unroll
    for (int e = 0; e < 4; e++){ p[e] /= s; probs[t * 4 + e] = p[e]; }
    int e0 = 0;
    for (int e = 1; e < 4; e++) if (p[e] > p[e0]) e0 = e;
    int e1 = -1;
    for (int e = 0; e < 4; e++){ if (e == e0) continue; if (e1 < 0 || p[e] > p[e1]) e1 = e; }
    float g = p[e0] + p[e1];
    topi[t * 2] = e0; topi[t * 2 + 1] = e1;
    #pragma unroll
    for (int e = 0; e < 4; e++)
      gatew[(size_t)e * TOK + t] = (e == e0) ? p[e0] / g : (e == e1) ? p[e1] / g : 0.f;
  }
}

// ---------------- sorted token lists (deterministic ballot compaction) ----------------
__global__ __launch_bounds__(256) void compact_stage(const int* __restrict__ topi,
                                                     int* __restrict__ stage,   // [4][32][256]
                                                     int* __restrict__ cnum){   // [4][32]
  const int c = blockIdx.x, tid = threadIdx.x;
  const int t = c * 256 + tid;
  const int lane = tid & 63, w = tid >> 6;
  const int e0 = topi[t * 2], e1 = topi[t * 2 + 1];
  __shared__ int wcnt[4][4], woff[4][4];
  int pos[4]; bool sel[4];
  #pragma unroll
  for (int e = 0; e < 4; e++){
    sel[e] = (e0 == e) || (e1 == e);
    unsigned long long m = __ballot(sel[e]);
    pos[e] = __popcll(m & ((1ull << lane) - 1ull));
    if (lane == 0) wcnt[e][w] = __popcll(m);
  }
  __syncthreads();
  if (tid < 4){
    int s = 0;
    #pragma unroll
    for (int ww = 0; ww < 4; ww++){ woff[tid][ww] = s; s += wcnt[tid][ww]; }
    cnum[tid * 32 + c] = s;
  }
  __syncthreads();
  #pragma unroll
  for (int e = 0; e < 4; e++)
    if (sel[e]) stage[(e * 32 + c) * 256 + woff[e][w] + pos[e]] = t;
}

__global__ __launch_bounds__(64) void scan_chunks(const int* __restrict__ cnum,
                                                  int* __restrict__ coff,   // [4][32]
                                                  int* __restrict__ cnt){   // [4]
  if (threadIdx.x < 4){
    int e = threadIdx.x, s = 0;
    for (int c = 0; c < 32; c++){ coff[e * 32 + c] = s; s += cnum[e * 32 + c]; }
    cnt[e] = s;
  }
}

__global__ __launch_bounds__(256) void compact_write(const int* __restrict__ stage,
                                                     const int* __restrict__ cnum,
                                                     const int* __restrict__ coff,
                                                     int* __restrict__ lists){
  const int c = blockIdx.x, tid = threadIdx.x;
  #pragma unroll
  for (int e = 0; e < 4; e++){
    const int n = cnum[e * 32 + c];
    if (tid < n)
      lists[e * TOK + coff[e * 32 + c] + tid] = stage[(e * 32 + c) * 256 + tid];
  }
}

// ---------------- aux loss ----------------
__global__ __launch_bounds__(256) void aux_kernel(const float* __restrict__ probs,
                                                  const int* __restrict__ topi,
                                                  float* __restrict__ out_aux){
  __shared__ float sp[4][256];
  __shared__ float sc[4][256];
  float p[4] = {0,0,0,0}, c[4] = {0,0,0,0};
  for (int t = threadIdx.x; t < TOK; t += 256){
    #pragma unroll
    for (int e = 0; e < 4; e++) p[e] += probs[t * 4 + e];
    c[topi[t * 2]]     += 1.f;
    c[topi[t * 2 + 1]] += 1.f;
  }
  #pragma unroll
  for (int e = 0; e < 4; e++){ sp[e][threadIdx.x] = p[e]; sc[e][threadIdx.x] = c[e]; }
  __syncthreads();
  for (int s = 128; s > 0; s >>= 1){
    if (threadIdx.x < (unsigned)s){
      #pragma unroll
      for (int e = 0; e < 4; e++){
        sp[e][threadIdx.x] += sp[e][threadIdx.x + s];
        sc[e][threadIdx.x] += sc[e][threadIdx.x + s];
      }
    }
    __syncthreads();
  }
  if (threadIdx.x == 0){
    float aux = 0.f;
    #pragma unroll
    for (int e = 0; e < 4; e++)
      aux += (sc[e][0] / (float)(TOK * 2)) * (sp[e][0] / (float)TOK);
    *out_aux = 4.f * aux;
  }
}

// =====================================================================
// Unified m97-style MoE GEMM — exact R16 kernel (best measured: 1587).
// 128x128 tile, BK=64, 256 thr (4 waves 2x2), single-buffered 32 KB
// (5 blk/CU), chunked XCD map, swizzled stage+read (0 conflicts),
// merged z=4. EPI 0: Hb non-temporal stores. EPI 1: atomicAdd
// (deterministic — exactly 2 commutative f32 addends on zeroed base).
// =====================================================================
template<int EPI, int N, int K, int ATOMIC>
__global__ __launch_bounds__(256) void gemm_97(
    const u16* __restrict__ A, const u16* __restrict__ BT,
    const int* __restrict__ lists, const int* __restrict__ cnt,
    const float* __restrict__ bias,
    u16* __restrict__ Hout,
    const float* __restrict__ gate, float* __restrict__ Cout)
{
  __shared__ __align__(16) u16 As[128 * 64];
  __shared__ __align__(16) u16 Bs[128 * 64];
  const int e = blockIdx.z;
  const int Mv = cnt[e];
  const int* rowidx = lists + (size_t)e * TOK;
  BT   += (size_t)e * N * K;
  bias += (size_t)e * N;
  if (EPI == 0) Hout += (size_t)e * CAPE * FFD;
  else        { A    += (size_t)e * CAPE * FFD; gate += (size_t)e * TOK; }

  const int gx = gridDim.x, gy = gridDim.y;
  const int orig = blockIdx.x + gx * blockIdx.y;
  const int xcd = orig & 7, rank = orig >> 3;          // gx*gy % 8 == 0
  const int bxl = rank / gy, by = rank % gy;
  const int bx = xcd * (gx >> 3) + bxl;                // chunked (R16)
  const int browg = by * 128;
  if (browg >= Mv) return;
  const size_t bcol = (size_t)bx * 128;

  const int tid = threadIdx.x, lane = tid & 63, w = tid >> 6;
  const int wr = w >> 1, wc = w & 1;
  const int l8 = lane >> 3;
  const int csw  = ((lane & 7) ^ l8) * 8;
  const int sw   = (lane & 7) * 8;
  const int h8   = ((lane >> 4) & 3) * 8;
  const int colk0 = h8 ^ sw, colk1 = (32 + h8) ^ sw;
  const int r16 = lane & 15;

  const u16* bsrc[4]; int bch[4];
  #pragma unroll
  for (int j = 0; j < 4; j++){
    int rb = j * 32 + w * 8;
    bch[j] = rb * 128;
    bsrc[j] = BT + (bcol + rb + l8) * (size_t)K + csw;
  }
  const u16* asrc[4]; int ach[4];
  #pragma unroll
  for (int q = 0; q < 4; q++){
    int rb = wr * 64 + q * 16 + wc * 8;
    ach[q] = rb * 128;
    int rl = browg + rb + l8;
    int ar;
    if (EPI == 0){
      if (rl > Mv - 1) rl = Mv - 1;
      ar = rowidx[rl];
    } else {
      ar = rl;
    }
    asrc[q] = A + (size_t)ar * K + csw;
  }

  f32x4 acc[4][4];
  #pragma unroll
  for (int m = 0; m < 4; m++)
    #pragma unroll
    for (int n = 0; n < 4; n++) acc[m][n] = (f32x4){0.f, 0.f, 0.f, 0.f};
  bf16x8 bC[8];

  const int NT = K / 64;
  for (int t = 0; t < NT; ++t){
    const size_t ko = (size_t)t * 64;
    __syncthreads();
    #pragma unroll
    for (int j = 0; j < 4; j++) gload_lds16(bsrc[j] + ko, (char*)Bs + bch[j]);
    #pragma unroll
    for (int q = 0; q < 4; q++) gload_lds16(asrc[q] + ko, (char*)As + ach[q]);
    __syncthreads();

    #pragma unroll
    for (int nf = 0; nf < 4; nf++){
      const u16* bp = Bs + (wc * 64 + nf * 16 + r16) * 64;
      bC[nf * 2]     = *(const bf16x8*)(bp + colk0);
      bC[nf * 2 + 1] = *(const bf16x8*)(bp + colk1);
    }
    #pragma unroll
    for (int m = 0; m < 4; m++){
      const u16* ap = As + (wr * 64 + m * 16 + r16) * 64;
      bf16x8 a0 = *(const bf16x8*)(ap + colk0);
      bf16x8 a1 = *(const bf16x8*)(ap + colk1);
      #pragma unroll
      for (int nf = 0; nf < 4; nf++){
        acc[m][nf] = mfma_bf16(a0, bC[nf * 2],     acc[m][nf]);
        acc[m][nf] = mfma_bf16(a1, bC[nf * 2 + 1], acc[m][nf]);
      }
    }
  }

  // epilogue
  const int cl = r16, rg = (lane >> 4) * 4;
  const size_t c0 = bcol + wc * 64;
  float bv[4];
  #pragma unroll
  for (int nf = 0; nf < 4; nf++) bv[nf] = bias[c0 + nf * 16 + cl];
  #pragma unroll
  for (int mf = 0; mf < 4; mf++){
    const int rbase = browg + wr * 64 + mf * 16 + rg;
    if (EPI == 0){
      #pragma unroll
      for (int nf = 0; nf < 4; nf++){
        const size_t col = c0 + nf * 16 + cl;
        #pragma unroll
        for (int j = 0; j < 4; j++){
          u16 hv = f2bf(gelu_tanh(acc[mf][nf][j] + bv[nf]));
          __builtin_nontemporal_store(hv, &Hout[(size_t)(rbase + j) * N + col]);
        }
      }
    } else {
      int   tok[4]; float gv[4];
      #pragma unroll
      for (int j = 0; j < 4; j++){
        const bool ok = (rbase + j) < Mv;
        tok[j] = ok ? rowidx[rbase + j] : -1;
        gv[j]  = ok ? gate[tok[j]] : 0.f;
      }
      #pragma unroll
      for (int nf = 0; nf < 4; nf++){
        const size_t col = c0 + nf * 16 + cl;
        #pragma unroll
        for (int j = 0; j < 4; j++){
          if (tok[j] >= 0){
            const size_t idx = (size_t)tok[j] * N + col;
            float y = gv[j] * (acc[mf][nf][j] + bv[nf]);
            if (ATOMIC) atomicAdd(Cout + idx, y);
            else        Cout[idx] += y;
          }
        }
      }
    }
  }
}

// ---------------- host ----------------
extern "C" void kernel_launch(void* const* d_in, const int* in_sizes, int n_in,
                              void* d_out, int out_size, void* d_ws, size_t ws_size,
                              hipStream_t stream){
  (void)in_sizes; (void)n_in;
  const float* X  = (const float*)d_in[0];
  const float* wg = (const float*)d_in[1];
  const float* bg = (const float*)d_in[2];
  const float* w1 = (const float*)d_in[3];
  const float* b1 = (const float*)d_in[4];
  const float* w2 = (const float*)d_in[5];
  const float* b2 = (const float*)d_in[6];
  float* out = (float*)d_out;

  char* ws = (char*)d_ws;
  size_t off = 0;
  auto alloc = [&](size_t b) -> char* {
    char* p = ws + off;
    off = (off + b + 255) & ~(size_t)255;
    return p;
  };
  u16*   Xb    = (u16*)  alloc((size_t)TOK * HD * 2);
  float* probs = (float*)alloc((size_t)TOK * 4 * 4);
  int*   topi  = (int*)  alloc((size_t)TOK * 2 * 4);
  float* gatew = (float*)alloc((size_t)NEXP * TOK * 4);
  int*   cnt   = (int*)  alloc((size_t)NEXP * 4);
  int*   lists = (int*)  alloc((size_t)NEXP * TOK * 4);
  int*   stage = (int*)  alloc((size_t)NEXP * 32 * 256 * 4);
  int*   cnum  = (int*)  alloc((size_t)NEXP * 32 * 4);
  int*   coff  = (int*)  alloc((size_t)NEXP * 32 * 4);
  const size_t common = off;

  const size_t w1t_all = (size_t)NEXP * FFD * HD * 2;
  const size_t w2t_all = (size_t)NEXP * HD * FFD * 2;
  const size_t hb_all  = (size_t)NEXP * CAPE * FFD * 2;
  const bool merged = ws_size >= common + w1t_all + w2t_all + hb_all + 1024;

  hipMemsetAsync(out, 0, (size_t)TOK * HD * sizeof(float), stream);

  router_kernel<<<TOK, 256, 0, stream>>>(X, wg, bg, probs, topi, gatew, Xb);
  compact_stage<<<32, 256, 0, stream>>>(topi, stage, cnum);
  scan_chunks<<<1, 64, 0, stream>>>(cnum, coff, cnt);
  compact_write<<<32, 256, 0, stream>>>(stage, cnum, coff, lists);
  aux_kernel<<<1, 256, 0, stream>>>(probs, topi, out + (out_size - 1));

  if (merged){
    u16* W1T = (u16*)alloc(w1t_all);
    u16* W2T = (u16*)alloc(w2t_all);
    u16* Hb  = (u16*)alloc(hb_all);
    transpose_cvt<<<dim3(FFD / 64, HD / 128, NEXP), 256, 0, stream>>>(w1, W1T, HD, FFD);
    transpose_cvt<<<dim3(HD / 64, FFD / 128, NEXP), 256, 0, stream>>>(w2, W2T, FFD, HD);
    gemm_97<0, FFD, HD, 0><<<dim3(FFD / 128, CAPE / 128, NEXP), 256, 0, stream>>>(
        Xb, W1T, lists, cnt, b1, Hb, nullptr, nullptr);
    gemm_97<1, HD, FFD, 1><<<dim3(HD / 128, CAPE / 128, NEXP), 256, 0, stream>>>(
        Hb, W2T, lists, cnt, b2, nullptr, gatew, out);
  } else {
    u16* W1T = (u16*)alloc((size_t)FFD * HD * 2);
    u16* W2T = (u16*)alloc((size_t)HD * FFD * 2);
    u16* Hb  = (u16*)alloc((size_t)CAPE * FFD * 2);
    for (int e = 0; e < NEXP; ++e){
      transpose_cvt<<<dim3(FFD / 64, HD / 128, 1), 256, 0, stream>>>(
          w1 + (size_t)e * HD * FFD, W1T, HD, FFD);
      transpose_cvt<<<dim3(HD / 64, FFD / 128, 1), 256, 0, stream>>>(
          w2 + (size_t)e * FFD * HD, W2T, FFD, HD);
      gemm_97<0, FFD, HD, 0><<<dim3(FFD / 128, CAPE / 128, 1), 256, 0, stream>>>(
          Xb, W1T, lists + e * TOK, cnt + e, b1 + (size_t)e * FFD,
          Hb, nullptr, nullptr);
      gemm_97<1, HD, FFD, 0><<<dim3(HD / 128, CAPE / 128, 1), 256, 0, stream>>>(
          Hb, W2T, lists + e * TOK, cnt + e, b2 + (size_t)e * HD,
          nullptr, gatew + (size_t)e * TOK, out);
    }
  }
}